// Round 3
// baseline (2909.325 us; speedup 1.0000x reference)
//
#include <hip/hip_runtime.h>
#include <hip/hip_bf16.h>
#include <cstring>
#include <cstdint>

#define N_NODES 100000
#define N_EDGES 1600000
#define HID 128
#define TOT (N_NODES * HID)   // 12,800,000

// ---------------- workspace layout (bytes) ----------------
// aggbuf  f32 [N,128]   @ 0           51,200,000   (ALIASED: t1 bf16[N,128] lives in
//                                                   first 25.6MB during layer 1; dead
//                                                   before aggbuf is written in layer 2)
// hbf     bf16[N,128]   @ 51,200,000  25,600,000
// counts  int [N]       @ 76,800,000     400,000
// partial int [N]       @ 77,200,000     400,000
// bsum    int [512]     @ 77,600,000       2,048
// offsets int [N+1]     @ 77,602,048     400,128
// cursor  int [N]       @ 78,002,176     400,000
// dinv    f32 [N]       @ 78,402,176     400,000
// sorted  int2[E]       @ 78,802,176  12,800,000
// total ~91.6 MB

// ---------------- helpers ----------------
__device__ __forceinline__ float2 ld2(const float* p) { return *(const float2*)p; }
__device__ __forceinline__ float2 ld2(const __hip_bfloat16* p) {
    const __hip_bfloat162 h = *(const __hip_bfloat162*)p;
    return make_float2(__bfloat162float(h.x), __bfloat162float(h.y));
}

__device__ __forceinline__ void store8(float* p, const float* v) {
    *(float4*)(p)     = make_float4(v[0], v[1], v[2], v[3]);
    *(float4*)(p + 4) = make_float4(v[4], v[5], v[6], v[7]);
}
__device__ __forceinline__ void store8(__hip_bfloat16* p, const float* v) {
    union { unsigned short us[8]; uint4 q; } u;
#pragma unroll
    for (int i = 0; i < 8; ++i) {
        __hip_bfloat16 b = __float2bfloat16(v[i]);
        unsigned short raw;
        memcpy(&raw, &b, 2);
        u.us[i] = raw;
    }
    *(uint4*)p = u.q;
}

// ---------------- CSR build ----------------
__global__ void k_count(const int* __restrict__ dst, int* __restrict__ counts) {
    int e = blockIdx.x * 256 + threadIdx.x;
    if (e < N_EDGES) atomicAdd(&counts[dst[e]], 1);
}

__global__ void k_scan_block(const int* __restrict__ counts, int* __restrict__ partial,
                             int* __restrict__ bsum) {
    __shared__ int s[256];
    int i = blockIdx.x * 256 + threadIdx.x;
    int v = (i < N_NODES) ? counts[i] : 0;
    s[threadIdx.x] = v;
    __syncthreads();
    for (int off = 1; off < 256; off <<= 1) {
        int t = (threadIdx.x >= off) ? s[threadIdx.x - off] : 0;
        __syncthreads();
        s[threadIdx.x] += t;
        __syncthreads();
    }
    if (i < N_NODES) partial[i] = s[threadIdx.x] - v;   // exclusive within block
    if (threadIdx.x == 255) bsum[blockIdx.x] = s[255];
}

__global__ void k_scan_sums(int* __restrict__ bsum, int nb) {
    __shared__ int s[512];
    int v = (threadIdx.x < nb) ? bsum[threadIdx.x] : 0;
    s[threadIdx.x] = v;
    __syncthreads();
    for (int off = 1; off < 512; off <<= 1) {
        int t = (threadIdx.x >= off) ? s[threadIdx.x - off] : 0;
        __syncthreads();
        s[threadIdx.x] += t;
        __syncthreads();
    }
    if (threadIdx.x < nb) bsum[threadIdx.x] = s[threadIdx.x] - v;  // exclusive
}

__global__ void k_finalize(const int* __restrict__ counts, const int* __restrict__ partial,
                           const int* __restrict__ bsum, int* __restrict__ offsets,
                           int* __restrict__ cursor, float* __restrict__ dinv) {
    int i = blockIdx.x * 256 + threadIdx.x;
    if (i < N_NODES) {
        int o = partial[i] + bsum[blockIdx.x];
        offsets[i] = o;
        cursor[i] = o;
        dinv[i] = rsqrtf((float)(counts[i] + 1));  // deg = in-degree + self loop
    }
    if (i == 0) offsets[N_NODES] = N_EDGES;
}

__global__ void k_scatter(const int* __restrict__ src, const int* __restrict__ dst,
                          const float* __restrict__ dinv, int* __restrict__ cursor,
                          int2* __restrict__ sorted) {
    int e = blockIdx.x * 256 + threadIdx.x;
    if (e < N_EDGES) {
        int s = src[e], d = dst[e];
        int pos = atomicAdd(&cursor[d], 1);
        float c = dinv[s] * dinv[d];
        sorted[pos] = make_int2(s, __float_as_int(c));
    }
}

// ---------------- aggregation: one wave per node, 2 features per lane ----------------
// Exact batches of 16 (16 gathers in flight), single clamped tail batch.
// Both aggregates now gather bf16 rows (256 B/row) thanks to the GEMM-first
// restructure of layer 1: S·(X W) = (S·X) W, so we compute t1 = x@W1 (bf16)
// first and aggregate that — halving layer-1 gather bytes vs f32 x.

#define AGG_BATCH(U)                                                              \
    {                                                                             \
        int2 sv[U];                                                               \
        float2 xs[U];                                                             \
        _Pragma("unroll") for (int i = 0; i < U; ++i) sv[i] = sorted[e + i];      \
        _Pragma("unroll") for (int i = 0; i < U; ++i)                             \
            xs[i] = ld2(Xf + (size_t)sv[i].x * HID);                              \
        _Pragma("unroll") for (int i = 0; i < U; ++i) {                           \
            float c = __int_as_float(sv[i].y);                                    \
            a0 = fmaf(c, xs[i].x, a0);                                            \
            a1 = fmaf(c, xs[i].y, a1);                                            \
        }                                                                         \
        e += U;                                                                   \
    }

#define AGG_BATCH_CLAMPED(U)                                                      \
    {                                                                             \
        int2 sv[U];                                                               \
        float2 xs[U];                                                             \
        _Pragma("unroll") for (int i = 0; i < U; ++i) {                           \
            int ee = e + i;                                                       \
            sv[i] = sorted[(ee < e1) ? ee : (e1 - 1)];                            \
        }                                                                         \
        _Pragma("unroll") for (int i = 0; i < U; ++i)                             \
            xs[i] = ld2(Xf + (size_t)sv[i].x * HID);                              \
        _Pragma("unroll") for (int i = 0; i < U; ++i) {                           \
            float c = (e + i < e1) ? __int_as_float(sv[i].y) : 0.f;               \
            a0 = fmaf(c, xs[i].x, a0);                                            \
            a1 = fmaf(c, xs[i].y, a1);                                            \
        }                                                                         \
    }

// core: computes a0,a1 = (S·X)[node][f..f+1] for lane-assigned feature pair
#define AGG_CORE(XTYPE)                                                           \
    int node = (blockIdx.x * 256 + threadIdx.x) >> 6;                             \
    int lane = threadIdx.x & 63;                                                  \
    if (node >= N_NODES) return;                                                  \
    int f = lane * 2;                                                             \
    const XTYPE* __restrict__ Xf = X + f;                                         \
    float di = dinv[node];                                                        \
    float sc = di * di;                                                           \
    float2 xi = ld2(Xf + (size_t)node * HID);                                     \
    float a0 = sc * xi.x, a1 = sc * xi.y;                                         \
    int e = offsets[node], e1 = offsets[node + 1];                                \
    int rem = e1 - e;                                                             \
    while (rem >= 16) {                                                           \
        AGG_BATCH(16);                                                            \
        rem -= 16;                                                                \
    }                                                                             \
    if (rem > 8) {                                                                \
        AGG_BATCH_CLAMPED(16);                                                    \
    } else if (rem > 0) {                                                         \
        AGG_BATCH_CLAMPED(8);                                                     \
    }

// layer-1 aggregate: gathers t1 (bf16), epilogue h = ELU(agg + b1), writes bf16
__global__ __launch_bounds__(256) void k_agg_h(const __hip_bfloat16* __restrict__ X,
                                               const int* __restrict__ offsets,
                                               const int2* __restrict__ sorted,
                                               const float* __restrict__ dinv,
                                               const float* __restrict__ b1,
                                               __hip_bfloat16* __restrict__ out) {
    AGG_CORE(__hip_bfloat16)
    float v0 = a0 + b1[f];
    float v1 = a1 + b1[f + 1];
    v0 = (v0 > 0.f) ? v0 : expm1f(v0);  // ELU(alpha=1)
    v1 = (v1 > 0.f) ? v1 : expm1f(v1);
    __hip_bfloat162 hb;
    hb.x = __float2bfloat16(v0);
    hb.y = __float2bfloat16(v1);
    *(__hip_bfloat162*)(out + (size_t)node * HID + f) = hb;
}

// layer-2 aggregate: gathers h (bf16), writes f32 aggbuf
__global__ __launch_bounds__(256) void k_agg_f32(const __hip_bfloat16* __restrict__ X,
                                                 const int* __restrict__ offsets,
                                                 const int2* __restrict__ sorted,
                                                 const float* __restrict__ dinv,
                                                 float* __restrict__ out) {
    AGG_CORE(__hip_bfloat16)
    *(float2*)(out + (size_t)node * HID + f) = make_float2(a0, a1);
}

// ---------------- GEMM: C[N,128] = A[N,128] @ W[128,128] (+ bias) ----------------
// proven geometry: 256 threads, tile 128x128, K chunked by 16 through LDS,
// thread = 8 rows x 8 cols. ACT: 0 = +bias, 1 = +bias+ELU, 2 = plain (no bias).
template <int ACT, typename OutT>
__global__ __launch_bounds__(256) void k_gemm(const float* __restrict__ A,
                                              const float* __restrict__ W,
                                              const float* __restrict__ bias,
                                              OutT* __restrict__ out) {
    __shared__ float Wl[16][128];
    __shared__ float Al[128][16];
    int t = threadIdx.x;
    int R = blockIdx.x * 128;
    int tx = t & 15, ty = t >> 4;
    int c0 = tx * 8;
    int r0 = ty * 8;
    float acc[8][8] = {};

    for (int k0 = 0; k0 < 128; k0 += 16) {
        {
            const float4* Wg = (const float4*)(W + k0 * 128);
            ((float4*)&Wl[0][0])[t] = Wg[t];
            ((float4*)&Wl[0][0])[t + 256] = Wg[t + 256];
        }
        {
#pragma unroll
            for (int ii = 0; ii < 2; ++ii) {
                int id = t + ii * 256;
                int row = id >> 2, c4 = (id & 3) * 4;
                int gr = R + row;
                float4 v = make_float4(0.f, 0.f, 0.f, 0.f);
                if (gr < N_NODES) v = *(const float4*)(A + (size_t)gr * HID + k0 + c4);
                *(float4*)(&Al[row][c4]) = v;
            }
        }
        __syncthreads();

#pragma unroll
        for (int kk4 = 0; kk4 < 4; ++kk4) {
            float4 av4[8];
#pragma unroll
            for (int j = 0; j < 8; ++j) av4[j] = *(const float4*)(&Al[r0 + j][kk4 * 4]);
            const float* av = (const float*)av4;  // av[j*4 + kk]
#pragma unroll
            for (int kk = 0; kk < 4; ++kk) {
                float4 b0 = *(const float4*)(&Wl[kk4 * 4 + kk][c0]);
                float4 b1 = *(const float4*)(&Wl[kk4 * 4 + kk][c0 + 4]);
#pragma unroll
                for (int j = 0; j < 8; ++j) {
                    float a = av[j * 4 + kk];
                    acc[j][0] = fmaf(a, b0.x, acc[j][0]);
                    acc[j][1] = fmaf(a, b0.y, acc[j][1]);
                    acc[j][2] = fmaf(a, b0.z, acc[j][2]);
                    acc[j][3] = fmaf(a, b0.w, acc[j][3]);
                    acc[j][4] = fmaf(a, b1.x, acc[j][4]);
                    acc[j][5] = fmaf(a, b1.y, acc[j][5]);
                    acc[j][6] = fmaf(a, b1.z, acc[j][6]);
                    acc[j][7] = fmaf(a, b1.w, acc[j][7]);
                }
            }
        }
        __syncthreads();
    }

    float bcol[8];
#pragma unroll
    for (int c = 0; c < 8; ++c) bcol[c] = (ACT == 2) ? 0.f : bias[c0 + c];
#pragma unroll
    for (int j = 0; j < 8; ++j) {
        int gr = R + r0 + j;
        if (gr >= N_NODES) continue;
        float v[8];
#pragma unroll
        for (int c = 0; c < 8; ++c) {
            float vv = acc[j][c] + bcol[c];
            if (ACT == 1) vv = (vv > 0.f) ? vv : expm1f(vv);  // ELU(alpha=1)
            v[c] = vv;
        }
        store8(out + (size_t)gr * HID + c0, v);
    }
}

// ---------------- Threefry-2x32 (20 rounds), key = (0, 42) ----------------
__device__ __forceinline__ unsigned rotl32(unsigned x, int r) {
    return (x << r) | (x >> (32 - r));
}

__device__ __forceinline__ void threefry2x32(unsigned x0, unsigned x1, unsigned& o0,
                                             unsigned& o1) {
    const unsigned ks0 = 0u, ks1 = 42u, ks2 = 0x1BD11BDAu ^ 42u;
    x0 += ks0;
    x1 += ks1;
    x0 += x1; x1 = rotl32(x1, 13); x1 ^= x0;
    x0 += x1; x1 = rotl32(x1, 15); x1 ^= x0;
    x0 += x1; x1 = rotl32(x1, 26); x1 ^= x0;
    x0 += x1; x1 = rotl32(x1, 6);  x1 ^= x0;
    x0 += ks1; x1 += ks2 + 1u;
    x0 += x1; x1 = rotl32(x1, 17); x1 ^= x0;
    x0 += x1; x1 = rotl32(x1, 29); x1 ^= x0;
    x0 += x1; x1 = rotl32(x1, 16); x1 ^= x0;
    x0 += x1; x1 = rotl32(x1, 24); x1 ^= x0;
    x0 += ks2; x1 += ks0 + 2u;
    x0 += x1; x1 = rotl32(x1, 13); x1 ^= x0;
    x0 += x1; x1 = rotl32(x1, 15); x1 ^= x0;
    x0 += x1; x1 = rotl32(x1, 26); x1 ^= x0;
    x0 += x1; x1 = rotl32(x1, 6);  x1 ^= x0;
    x0 += ks0; x1 += ks1 + 3u;
    x0 += x1; x1 = rotl32(x1, 17); x1 ^= x0;
    x0 += x1; x1 = rotl32(x1, 29); x1 ^= x0;
    x0 += x1; x1 = rotl32(x1, 16); x1 ^= x0;
    x0 += x1; x1 = rotl32(x1, 24); x1 ^= x0;
    x0 += ks1; x1 += ks2 + 4u;
    x0 += x1; x1 = rotl32(x1, 13); x1 ^= x0;
    x0 += x1; x1 = rotl32(x1, 15); x1 ^= x0;
    x0 += x1; x1 = rotl32(x1, 26); x1 ^= x0;
    x0 += x1; x1 = rotl32(x1, 6);  x1 ^= x0;
    x0 += ks2; x1 += ks0 + 5u;
    o0 = x0;
    o1 = x1;
}

// XLA ErfInv (f32, Giles) — matches CPU XLA expansion used by jax.random.normal.
__device__ __forceinline__ float erfinv_f32(float x) {
    float w = -log1pf(-x * x);
    float p;
    if (w < 5.0f) {
        w -= 2.5f;
        p = 2.81022636e-08f;
        p = fmaf(p, w, 3.43273939e-07f);
        p = fmaf(p, w, -3.5233877e-06f);
        p = fmaf(p, w, -4.39150654e-06f);
        p = fmaf(p, w, 0.00021858087f);
        p = fmaf(p, w, -0.00125372503f);
        p = fmaf(p, w, -0.00417768164f);
        p = fmaf(p, w, 0.246640727f);
        p = fmaf(p, w, 1.50140941f);
    } else {
        w = sqrtf(w) - 3.0f;
        p = -0.000200214257f;
        p = fmaf(p, w, 0.000100950558f);
        p = fmaf(p, w, 0.00134934322f);
        p = fmaf(p, w, -0.00367342844f);
        p = fmaf(p, w, 0.00573950773f);
        p = fmaf(p, w, -0.0076224613f);
        p = fmaf(p, w, 0.00943887047f);
        p = fmaf(p, w, 1.00167406f);
        p = fmaf(p, w, 2.83297682f);
    }
    return p * x;
}

__device__ __forceinline__ float sample_eps(unsigned j) {
    unsigned o0, o1;
    threefry2x32(0u, j, o0, o1);
    unsigned bits = o0 ^ o1;
    float f = __uint_as_float((bits >> 9) | 0x3f800000u) - 1.0f;
    float u = f * 2.0f - 0.99999994f;
    u = fmaxf(u, -0.99999994f);
    return 1.41421356f * erfinv_f32(u);
}

// ---------------- lv GEMM + reparameterize (proven 128x128 geometry) ----------------
// lv = A @ Wlv + blv; z = mu + eps * exp(0.5*lv). Reads mu (just written, L2/L3-hot)
// in the epilogue — replaces the separate k_sample pass (saves its 102 MB re-read).
__global__ __launch_bounds__(256) void k_gemm_lv_sample(const float* __restrict__ A,
                                                        const float* __restrict__ W,
                                                        const float* __restrict__ bias,
                                                        const float* __restrict__ mu,
                                                        float* __restrict__ lv,
                                                        float* __restrict__ z) {
    __shared__ float Wl[16][128];
    __shared__ float Al[128][16];
    int t = threadIdx.x;
    int R = blockIdx.x * 128;
    int tx = t & 15, ty = t >> 4;
    int c0 = tx * 8;
    int r0 = ty * 8;
    float acc[8][8] = {};

    for (int k0 = 0; k0 < 128; k0 += 16) {
        {
            const float4* Wg = (const float4*)(W + k0 * 128);
            ((float4*)&Wl[0][0])[t] = Wg[t];
            ((float4*)&Wl[0][0])[t + 256] = Wg[t + 256];
        }
        {
#pragma unroll
            for (int ii = 0; ii < 2; ++ii) {
                int id = t + ii * 256;
                int row = id >> 2, c4 = (id & 3) * 4;
                int gr = R + row;
                float4 v = make_float4(0.f, 0.f, 0.f, 0.f);
                if (gr < N_NODES) v = *(const float4*)(A + (size_t)gr * HID + k0 + c4);
                *(float4*)(&Al[row][c4]) = v;
            }
        }
        __syncthreads();

#pragma unroll
        for (int kk4 = 0; kk4 < 4; ++kk4) {
            float4 av4[8];
#pragma unroll
            for (int j = 0; j < 8; ++j) av4[j] = *(const float4*)(&Al[r0 + j][kk4 * 4]);
            const float* av = (const float*)av4;
#pragma unroll
            for (int kk = 0; kk < 4; ++kk) {
                float4 b0 = *(const float4*)(&Wl[kk4 * 4 + kk][c0]);
                float4 b1 = *(const float4*)(&Wl[kk4 * 4 + kk][c0 + 4]);
#pragma unroll
                for (int j = 0; j < 8; ++j) {
                    float a = av[j * 4 + kk];
                    acc[j][0] = fmaf(a, b0.x, acc[j][0]);
                    acc[j][1] = fmaf(a, b0.y, acc[j][1]);
                    acc[j][2] = fmaf(a, b0.z, acc[j][2]);
                    acc[j][3] = fmaf(a, b0.w, acc[j][3]);
                    acc[j][4] = fmaf(a, b1.x, acc[j][4]);
                    acc[j][5] = fmaf(a, b1.y, acc[j][5]);
                    acc[j][6] = fmaf(a, b1.z, acc[j][6]);
                    acc[j][7] = fmaf(a, b1.w, acc[j][7]);
                }
            }
        }
        __syncthreads();
    }

    float bcol[8];
#pragma unroll
    for (int c = 0; c < 8; ++c) bcol[c] = bias[c0 + c];
#pragma unroll
    for (int j = 0; j < 8; ++j) {
        int gr = R + r0 + j;
        if (gr >= N_NODES) continue;
        size_t base = (size_t)gr * HID + c0;
        float4 m0 = *(const float4*)(mu + base);
        float4 m1 = *(const float4*)(mu + base + 4);
        float mv[8] = {m0.x, m0.y, m0.z, m0.w, m1.x, m1.y, m1.z, m1.w};
        float vlv[8], vz[8];
#pragma unroll
        for (int c = 0; c < 8; ++c) {
            float l = acc[j][c] + bcol[c];
            float eps = sample_eps((unsigned)gr * 128u + (unsigned)(c0 + c));
            vlv[c] = l;
            vz[c] = fmaf(eps, expf(0.5f * l), mv[c]);
        }
        store8(lv + base, vlv);
        store8(z + base, vz);
    }
}

// ---------------- launch ----------------
extern "C" void kernel_launch(void* const* d_in, const int* in_sizes, int n_in,
                              void* d_out, int out_size, void* d_ws, size_t ws_size,
                              hipStream_t stream) {
    const float* x = (const float*)d_in[0];
    const int* ei = (const int*)d_in[1];
    const float* W1 = (const float*)d_in[2];
    const float* b1 = (const float*)d_in[3];
    const float* Wmu = (const float*)d_in[4];
    const float* bmu = (const float*)d_in[5];
    const float* Wlv = (const float*)d_in[6];
    const float* blv = (const float*)d_in[7];

    float* z = (float*)d_out;
    float* mu = z + (size_t)TOT;
    float* lv = z + 2 * (size_t)TOT;

    char* ws = (char*)d_ws;
    float* aggbuf = (float*)(ws + 0ull);
    __hip_bfloat16* t1buf = (__hip_bfloat16*)(ws + 0ull);  // aliases aggbuf (see layout)
    __hip_bfloat16* hbf = (__hip_bfloat16*)(ws + 51200000ull);
    int* counts = (int*)(ws + 76800000ull);
    int* partial = (int*)(ws + 77200000ull);
    int* bsum = (int*)(ws + 77600000ull);
    int* offsets = (int*)(ws + 77602048ull);
    int* cursor = (int*)(ws + 78002176ull);
    float* dinv = (float*)(ws + 78402176ull);
    int2* sorted = (int2*)(ws + 78802176ull);

    const int* src = ei;
    const int* dst = ei + N_EDGES;

    const int NBLK = (N_NODES + 255) / 256;  // 391
    const int AGG_GRID = (N_NODES * 64 + 255) / 256;
    const int GEMM_GRID = (N_NODES + 127) / 128;

    hipMemsetAsync(counts, 0, N_NODES * sizeof(int), stream);
    k_count<<<(N_EDGES + 255) / 256, 256, 0, stream>>>(dst, counts);
    k_scan_block<<<NBLK, 256, 0, stream>>>(counts, partial, bsum);
    k_scan_sums<<<1, 512, 0, stream>>>(bsum, NBLK);
    k_finalize<<<NBLK, 256, 0, stream>>>(counts, partial, bsum, offsets, cursor, dinv);
    k_scatter<<<(N_EDGES + 255) / 256, 256, 0, stream>>>(src, dst, dinv, cursor, sorted);

    // layer 1 (commuted): t1 = x @ W1 (bf16); h = ELU(S·t1 + b1) (bf16)
    k_gemm<2, __hip_bfloat16><<<GEMM_GRID, 256, 0, stream>>>(x, W1, b1, t1buf);
    k_agg_h<<<AGG_GRID, 256, 0, stream>>>(t1buf, offsets, sorted, dinv, b1, hbf);

    // layer 2: ha = S·h (f32, overwrites t1 region); mu; lv + z
    k_agg_f32<<<AGG_GRID, 256, 0, stream>>>(hbf, offsets, sorted, dinv, aggbuf);
    k_gemm<0, float><<<GEMM_GRID, 256, 0, stream>>>(aggbuf, Wmu, bmu, mu);
    k_gemm_lv_sample<<<GEMM_GRID, 256, 0, stream>>>(aggbuf, Wlv, blv, mu, lv, z);
}

// Round 4
// 692.367 us; speedup vs baseline: 4.2020x; 4.2020x over previous
//
#include <hip/hip_runtime.h>
#include <hip/hip_bf16.h>
#include <cstring>
#include <cstdint>

#define N_NODES 100000
#define N_EDGES 1600000
#define HID 128
#define TOT (N_NODES * HID)   // 12,800,000

// ---------------- workspace layout (bytes) ----------------
// aggbuf  f32 [N,128]   @ 0           51,200,000   (ALIASED: t1 bf16[N,128] lives in
//                                                   first 25.6MB during layer 1; dead
//                                                   before aggbuf is written in layer 2)
// hbf     bf16[N,128]   @ 51,200,000  25,600,000
// counts  int [N]       @ 76,800,000     400,000
// partial int [N]       @ 77,200,000     400,000
// bsum    int [512]     @ 77,600,000       2,048
// offsets int [N+1]     @ 77,602,048     400,128
// cursor  int [N]       @ 78,002,176     400,000
// dinv    f32 [N]       @ 78,402,176     400,000
// sorted  int2[E]       @ 78,802,176  12,800,000
// total ~91.6 MB

// NOTE (round-3 lesson): fusing threefry/erfinv/expf into the GEMM epilogue made the
// register allocator spill acc[8][8] to scratch (VGPR_Count 72->36, 9.9 GB scratch
// traffic, 2408 us). Sampling stays a standalone pass; GEMMs stay epilogue-light.

// ---------------- helpers ----------------
__device__ __forceinline__ float2 ld2(const float* p) { return *(const float2*)p; }
__device__ __forceinline__ float2 ld2(const __hip_bfloat16* p) {
    const __hip_bfloat162 h = *(const __hip_bfloat162*)p;
    return make_float2(__bfloat162float(h.x), __bfloat162float(h.y));
}

__device__ __forceinline__ void store8(float* p, const float* v) {
    *(float4*)(p)     = make_float4(v[0], v[1], v[2], v[3]);
    *(float4*)(p + 4) = make_float4(v[4], v[5], v[6], v[7]);
}
__device__ __forceinline__ void store8(__hip_bfloat16* p, const float* v) {
    union { unsigned short us[8]; uint4 q; } u;
#pragma unroll
    for (int i = 0; i < 8; ++i) {
        __hip_bfloat16 b = __float2bfloat16(v[i]);
        unsigned short raw;
        memcpy(&raw, &b, 2);
        u.us[i] = raw;
    }
    *(uint4*)p = u.q;
}

// ---------------- CSR build ----------------
__global__ void k_count(const int* __restrict__ dst, int* __restrict__ counts) {
    int e = blockIdx.x * 256 + threadIdx.x;
    if (e < N_EDGES) atomicAdd(&counts[dst[e]], 1);
}

__global__ void k_scan_block(const int* __restrict__ counts, int* __restrict__ partial,
                             int* __restrict__ bsum) {
    __shared__ int s[256];
    int i = blockIdx.x * 256 + threadIdx.x;
    int v = (i < N_NODES) ? counts[i] : 0;
    s[threadIdx.x] = v;
    __syncthreads();
    for (int off = 1; off < 256; off <<= 1) {
        int t = (threadIdx.x >= off) ? s[threadIdx.x - off] : 0;
        __syncthreads();
        s[threadIdx.x] += t;
        __syncthreads();
    }
    if (i < N_NODES) partial[i] = s[threadIdx.x] - v;   // exclusive within block
    if (threadIdx.x == 255) bsum[blockIdx.x] = s[255];
}

__global__ void k_scan_sums(int* __restrict__ bsum, int nb) {
    __shared__ int s[512];
    int v = (threadIdx.x < nb) ? bsum[threadIdx.x] : 0;
    s[threadIdx.x] = v;
    __syncthreads();
    for (int off = 1; off < 512; off <<= 1) {
        int t = (threadIdx.x >= off) ? s[threadIdx.x - off] : 0;
        __syncthreads();
        s[threadIdx.x] += t;
        __syncthreads();
    }
    if (threadIdx.x < nb) bsum[threadIdx.x] = s[threadIdx.x] - v;  // exclusive
}

__global__ void k_finalize(const int* __restrict__ counts, const int* __restrict__ partial,
                           const int* __restrict__ bsum, int* __restrict__ offsets,
                           int* __restrict__ cursor, float* __restrict__ dinv) {
    int i = blockIdx.x * 256 + threadIdx.x;
    if (i < N_NODES) {
        int o = partial[i] + bsum[blockIdx.x];
        offsets[i] = o;
        cursor[i] = o;
        dinv[i] = rsqrtf((float)(counts[i] + 1));  // deg = in-degree + self loop
    }
    if (i == 0) offsets[N_NODES] = N_EDGES;
}

__global__ void k_scatter(const int* __restrict__ src, const int* __restrict__ dst,
                          const float* __restrict__ dinv, int* __restrict__ cursor,
                          int2* __restrict__ sorted) {
    int e = blockIdx.x * 256 + threadIdx.x;
    if (e < N_EDGES) {
        int s = src[e], d = dst[e];
        int pos = atomicAdd(&cursor[d], 1);
        float c = dinv[s] * dinv[d];
        sorted[pos] = make_int2(s, __float_as_int(c));
    }
}

// ---------------- aggregation: one wave per node, 2 features per lane ----------------
// Exact batches of 16 (16 gathers in flight), single clamped tail batch.
// Both aggregates gather bf16 rows (256 B/row) thanks to the GEMM-first
// restructure of layer 1: S·(X W) = (S·X) W, so we compute t1 = x@W1 (bf16)
// first and aggregate that — halving layer-1 gather bytes vs f32 x.

#define AGG_BATCH(U)                                                              \
    {                                                                             \
        int2 sv[U];                                                               \
        float2 xs[U];                                                             \
        _Pragma("unroll") for (int i = 0; i < U; ++i) sv[i] = sorted[e + i];      \
        _Pragma("unroll") for (int i = 0; i < U; ++i)                             \
            xs[i] = ld2(Xf + (size_t)sv[i].x * HID);                              \
        _Pragma("unroll") for (int i = 0; i < U; ++i) {                           \
            float c = __int_as_float(sv[i].y);                                    \
            a0 = fmaf(c, xs[i].x, a0);                                            \
            a1 = fmaf(c, xs[i].y, a1);                                            \
        }                                                                         \
        e += U;                                                                   \
    }

#define AGG_BATCH_CLAMPED(U)                                                      \
    {                                                                             \
        int2 sv[U];                                                               \
        float2 xs[U];                                                             \
        _Pragma("unroll") for (int i = 0; i < U; ++i) {                           \
            int ee = e + i;                                                       \
            sv[i] = sorted[(ee < e1) ? ee : (e1 - 1)];                            \
        }                                                                         \
        _Pragma("unroll") for (int i = 0; i < U; ++i)                             \
            xs[i] = ld2(Xf + (size_t)sv[i].x * HID);                              \
        _Pragma("unroll") for (int i = 0; i < U; ++i) {                           \
            float c = (e + i < e1) ? __int_as_float(sv[i].y) : 0.f;               \
            a0 = fmaf(c, xs[i].x, a0);                                            \
            a1 = fmaf(c, xs[i].y, a1);                                            \
        }                                                                         \
    }

// core: computes a0,a1 = (S·X)[node][f..f+1] for lane-assigned feature pair
#define AGG_CORE(XTYPE)                                                           \
    int node = (blockIdx.x * 256 + threadIdx.x) >> 6;                             \
    int lane = threadIdx.x & 63;                                                  \
    if (node >= N_NODES) return;                                                  \
    int f = lane * 2;                                                             \
    const XTYPE* __restrict__ Xf = X + f;                                         \
    float di = dinv[node];                                                        \
    float sc = di * di;                                                           \
    float2 xi = ld2(Xf + (size_t)node * HID);                                     \
    float a0 = sc * xi.x, a1 = sc * xi.y;                                         \
    int e = offsets[node], e1 = offsets[node + 1];                                \
    int rem = e1 - e;                                                             \
    while (rem >= 16) {                                                           \
        AGG_BATCH(16);                                                            \
        rem -= 16;                                                                \
    }                                                                             \
    if (rem > 8) {                                                                \
        AGG_BATCH_CLAMPED(16);                                                    \
    } else if (rem > 0) {                                                         \
        AGG_BATCH_CLAMPED(8);                                                     \
    }

// layer-1 aggregate: gathers t1 (bf16), epilogue h = ELU(agg + b1), writes bf16
__global__ __launch_bounds__(256) void k_agg_h(const __hip_bfloat16* __restrict__ X,
                                               const int* __restrict__ offsets,
                                               const int2* __restrict__ sorted,
                                               const float* __restrict__ dinv,
                                               const float* __restrict__ b1,
                                               __hip_bfloat16* __restrict__ out) {
    AGG_CORE(__hip_bfloat16)
    float v0 = a0 + b1[f];
    float v1 = a1 + b1[f + 1];
    v0 = (v0 > 0.f) ? v0 : expm1f(v0);  // ELU(alpha=1)
    v1 = (v1 > 0.f) ? v1 : expm1f(v1);
    __hip_bfloat162 hb;
    hb.x = __float2bfloat16(v0);
    hb.y = __float2bfloat16(v1);
    *(__hip_bfloat162*)(out + (size_t)node * HID + f) = hb;
}

// layer-2 aggregate: gathers h (bf16), writes f32 aggbuf
__global__ __launch_bounds__(256) void k_agg_f32(const __hip_bfloat16* __restrict__ X,
                                                 const int* __restrict__ offsets,
                                                 const int2* __restrict__ sorted,
                                                 const float* __restrict__ dinv,
                                                 float* __restrict__ out) {
    AGG_CORE(__hip_bfloat16)
    *(float2*)(out + (size_t)node * HID + f) = make_float2(a0, a1);
}

// ---------------- GEMM: C[N,128] = A[N,128] @ W[128,128] (+ bias) ----------------
// proven geometry: 256 threads, tile 128x128, K chunked by 16 through LDS,
// thread = 8 rows x 8 cols. ACT: 0 = +bias, 1 = +bias+ELU, 2 = plain (no bias).
template <int ACT, typename OutT>
__global__ __launch_bounds__(256) void k_gemm(const float* __restrict__ A,
                                              const float* __restrict__ W,
                                              const float* __restrict__ bias,
                                              OutT* __restrict__ out) {
    __shared__ float Wl[16][128];
    __shared__ float Al[128][16];
    int t = threadIdx.x;
    int R = blockIdx.x * 128;
    int tx = t & 15, ty = t >> 4;
    int c0 = tx * 8;
    int r0 = ty * 8;
    float acc[8][8] = {};

    for (int k0 = 0; k0 < 128; k0 += 16) {
        {
            const float4* Wg = (const float4*)(W + k0 * 128);
            ((float4*)&Wl[0][0])[t] = Wg[t];
            ((float4*)&Wl[0][0])[t + 256] = Wg[t + 256];
        }
        {
#pragma unroll
            for (int ii = 0; ii < 2; ++ii) {
                int id = t + ii * 256;
                int row = id >> 2, c4 = (id & 3) * 4;
                int gr = R + row;
                float4 v = make_float4(0.f, 0.f, 0.f, 0.f);
                if (gr < N_NODES) v = *(const float4*)(A + (size_t)gr * HID + k0 + c4);
                *(float4*)(&Al[row][c4]) = v;
            }
        }
        __syncthreads();

#pragma unroll
        for (int kk4 = 0; kk4 < 4; ++kk4) {
            float4 av4[8];
#pragma unroll
            for (int j = 0; j < 8; ++j) av4[j] = *(const float4*)(&Al[r0 + j][kk4 * 4]);
            const float* av = (const float*)av4;  // av[j*4 + kk]
#pragma unroll
            for (int kk = 0; kk < 4; ++kk) {
                float4 b0 = *(const float4*)(&Wl[kk4 * 4 + kk][c0]);
                float4 b1 = *(const float4*)(&Wl[kk4 * 4 + kk][c0 + 4]);
#pragma unroll
                for (int j = 0; j < 8; ++j) {
                    float a = av[j * 4 + kk];
                    acc[j][0] = fmaf(a, b0.x, acc[j][0]);
                    acc[j][1] = fmaf(a, b0.y, acc[j][1]);
                    acc[j][2] = fmaf(a, b0.z, acc[j][2]);
                    acc[j][3] = fmaf(a, b0.w, acc[j][3]);
                    acc[j][4] = fmaf(a, b1.x, acc[j][4]);
                    acc[j][5] = fmaf(a, b1.y, acc[j][5]);
                    acc[j][6] = fmaf(a, b1.z, acc[j][6]);
                    acc[j][7] = fmaf(a, b1.w, acc[j][7]);
                }
            }
        }
        __syncthreads();
    }

    float bcol[8];
#pragma unroll
    for (int c = 0; c < 8; ++c) bcol[c] = (ACT == 2) ? 0.f : bias[c0 + c];
#pragma unroll
    for (int j = 0; j < 8; ++j) {
        int gr = R + r0 + j;
        if (gr >= N_NODES) continue;
        float v[8];
#pragma unroll
        for (int c = 0; c < 8; ++c) {
            float vv = acc[j][c] + bcol[c];
            if (ACT == 1) vv = (vv > 0.f) ? vv : expm1f(vv);  // ELU(alpha=1)
            v[c] = vv;
        }
        store8(out + (size_t)gr * HID + c0, v);
    }
}

// ---------------- Threefry-2x32 (20 rounds), key = (0, 42) ----------------
__device__ __forceinline__ unsigned rotl32(unsigned x, int r) {
    return (x << r) | (x >> (32 - r));
}

__device__ __forceinline__ void threefry2x32(unsigned x0, unsigned x1, unsigned& o0,
                                             unsigned& o1) {
    const unsigned ks0 = 0u, ks1 = 42u, ks2 = 0x1BD11BDAu ^ 42u;
    x0 += ks0;
    x1 += ks1;
    x0 += x1; x1 = rotl32(x1, 13); x1 ^= x0;
    x0 += x1; x1 = rotl32(x1, 15); x1 ^= x0;
    x0 += x1; x1 = rotl32(x1, 26); x1 ^= x0;
    x0 += x1; x1 = rotl32(x1, 6);  x1 ^= x0;
    x0 += ks1; x1 += ks2 + 1u;
    x0 += x1; x1 = rotl32(x1, 17); x1 ^= x0;
    x0 += x1; x1 = rotl32(x1, 29); x1 ^= x0;
    x0 += x1; x1 = rotl32(x1, 16); x1 ^= x0;
    x0 += x1; x1 = rotl32(x1, 24); x1 ^= x0;
    x0 += ks2; x1 += ks0 + 2u;
    x0 += x1; x1 = rotl32(x1, 13); x1 ^= x0;
    x0 += x1; x1 = rotl32(x1, 15); x1 ^= x0;
    x0 += x1; x1 = rotl32(x1, 26); x1 ^= x0;
    x0 += x1; x1 = rotl32(x1, 6);  x1 ^= x0;
    x0 += ks0; x1 += ks1 + 3u;
    x0 += x1; x1 = rotl32(x1, 17); x1 ^= x0;
    x0 += x1; x1 = rotl32(x1, 29); x1 ^= x0;
    x0 += x1; x1 = rotl32(x1, 16); x1 ^= x0;
    x0 += x1; x1 = rotl32(x1, 24); x1 ^= x0;
    x0 += ks1; x1 += ks2 + 4u;
    x0 += x1; x1 = rotl32(x1, 13); x1 ^= x0;
    x0 += x1; x1 = rotl32(x1, 15); x1 ^= x0;
    x0 += x1; x1 = rotl32(x1, 26); x1 ^= x0;
    x0 += x1; x1 = rotl32(x1, 6);  x1 ^= x0;
    x0 += ks2; x1 += ks0 + 5u;
    o0 = x0;
    o1 = x1;
}

// XLA ErfInv (f32, Giles) — matches CPU XLA expansion used by jax.random.normal.
__device__ __forceinline__ float erfinv_f32(float x) {
    float w = -log1pf(-x * x);
    float p;
    if (w < 5.0f) {
        w -= 2.5f;
        p = 2.81022636e-08f;
        p = fmaf(p, w, 3.43273939e-07f);
        p = fmaf(p, w, -3.5233877e-06f);
        p = fmaf(p, w, -4.39150654e-06f);
        p = fmaf(p, w, 0.00021858087f);
        p = fmaf(p, w, -0.00125372503f);
        p = fmaf(p, w, -0.00417768164f);
        p = fmaf(p, w, 0.246640727f);
        p = fmaf(p, w, 1.50140941f);
    } else {
        w = sqrtf(w) - 3.0f;
        p = -0.000200214257f;
        p = fmaf(p, w, 0.000100950558f);
        p = fmaf(p, w, 0.00134934322f);
        p = fmaf(p, w, -0.00367342844f);
        p = fmaf(p, w, 0.00573950773f);
        p = fmaf(p, w, -0.0076224613f);
        p = fmaf(p, w, 0.00943887047f);
        p = fmaf(p, w, 1.00167406f);
        p = fmaf(p, w, 2.83297682f);
    }
    return p * x;
}

__global__ __launch_bounds__(256) void k_sample(const float* __restrict__ mu,
                                                const float* __restrict__ lv,
                                                float* __restrict__ z) {
    int j = blockIdx.x * 256 + threadIdx.x;
    if (j >= TOT) return;
    unsigned o0, o1;
    threefry2x32(0u, (unsigned)j, o0, o1);
    unsigned bits = o0 ^ o1;
    // uniform in [minval, 1) with minval = nextafter(-1,0); scale rounds to 2.0f
    float f = __uint_as_float((bits >> 9) | 0x3f800000u) - 1.0f;
    float u = f * 2.0f - 0.99999994f;
    u = fmaxf(u, -0.99999994f);
    float eps = 1.41421356f * erfinv_f32(u);
    z[j] = fmaf(eps, expf(0.5f * lv[j]), mu[j]);
}

// ---------------- launch ----------------
extern "C" void kernel_launch(void* const* d_in, const int* in_sizes, int n_in,
                              void* d_out, int out_size, void* d_ws, size_t ws_size,
                              hipStream_t stream) {
    const float* x = (const float*)d_in[0];
    const int* ei = (const int*)d_in[1];
    const float* W1 = (const float*)d_in[2];
    const float* b1 = (const float*)d_in[3];
    const float* Wmu = (const float*)d_in[4];
    const float* bmu = (const float*)d_in[5];
    const float* Wlv = (const float*)d_in[6];
    const float* blv = (const float*)d_in[7];

    float* z = (float*)d_out;
    float* mu = z + (size_t)TOT;
    float* lv = z + 2 * (size_t)TOT;

    char* ws = (char*)d_ws;
    float* aggbuf = (float*)(ws + 0ull);
    __hip_bfloat16* t1buf = (__hip_bfloat16*)(ws + 0ull);  // aliases aggbuf (see layout)
    __hip_bfloat16* hbf = (__hip_bfloat16*)(ws + 51200000ull);
    int* counts = (int*)(ws + 76800000ull);
    int* partial = (int*)(ws + 77200000ull);
    int* bsum = (int*)(ws + 77600000ull);
    int* offsets = (int*)(ws + 77602048ull);
    int* cursor = (int*)(ws + 78002176ull);
    float* dinv = (float*)(ws + 78402176ull);
    int2* sorted = (int2*)(ws + 78802176ull);

    const int* src = ei;
    const int* dst = ei + N_EDGES;

    const int NBLK = (N_NODES + 255) / 256;  // 391
    const int AGG_GRID = (N_NODES * 64 + 255) / 256;
    const int GEMM_GRID = (N_NODES + 127) / 128;

    hipMemsetAsync(counts, 0, N_NODES * sizeof(int), stream);
    k_count<<<(N_EDGES + 255) / 256, 256, 0, stream>>>(dst, counts);
    k_scan_block<<<NBLK, 256, 0, stream>>>(counts, partial, bsum);
    k_scan_sums<<<1, 512, 0, stream>>>(bsum, NBLK);
    k_finalize<<<NBLK, 256, 0, stream>>>(counts, partial, bsum, offsets, cursor, dinv);
    k_scatter<<<(N_EDGES + 255) / 256, 256, 0, stream>>>(src, dst, dinv, cursor, sorted);

    // layer 1 (commuted): t1 = x @ W1 (bf16); h = ELU(S·t1 + b1) (bf16)
    k_gemm<2, __hip_bfloat16><<<GEMM_GRID, 256, 0, stream>>>(x, W1, b1, t1buf);
    k_agg_h<<<AGG_GRID, 256, 0, stream>>>(t1buf, offsets, sorted, dinv, b1, hbf);

    // layer 2: ha = S·h (f32, overwrites t1 region); mu; lv
    k_agg_f32<<<AGG_GRID, 256, 0, stream>>>(hbf, offsets, sorted, dinv, aggbuf);
    k_gemm<0, float><<<GEMM_GRID, 256, 0, stream>>>(aggbuf, Wmu, bmu, mu);
    k_gemm<0, float><<<GEMM_GRID, 256, 0, stream>>>(aggbuf, Wlv, blv, lv);

    // z = mu + eps * exp(0.5*lv)   (eps = threefry-normal, key 42); mu/lv L3-hot
    k_sample<<<(TOT + 255) / 256, 256, 0, stream>>>(mu, lv, z);
}

// Round 5
// 621.491 us; speedup vs baseline: 4.6812x; 1.1140x over previous
//
#include <hip/hip_runtime.h>
#include <hip/hip_bf16.h>
#include <cstring>
#include <cstdint>

#define N_NODES 100000
#define N_EDGES 1600000
#define HID 128
#define TOT (N_NODES * HID)   // 12,800,000
#define GEMM_GRID_C 782       // (N_NODES + 127) / 128
#define SCAT_GRID_C 6250      // N_EDGES / 256

// ---------------- workspace layout (bytes) ----------------
// aggbuf  f32 [N,128]   @ 0           51,200,000
//   ALIASED: t1 bf16[N,128] in [0, 25.6MB) during layer 1 (dead before agg_f32);
//            rank int[E]    in [25.6MB, 32MB) during CSR build (dead after scatter)
// hbf     bf16[N,128]   @ 51,200,000  25,600,000
// counts  int [N]       @ 76,800,000     400,000
// partial int [N]       @ 77,200,000     400,000
// bsum    int [512]     @ 77,600,000       2,048
// offsets int [N+1]     @ 77,602,048     400,128
// (cursor slot unused)  @ 78,002,176     400,000
// dinv    f32 [N]       @ 78,402,176     400,000
// sorted  int2[E]       @ 78,802,176  12,800,000
// total ~91.6 MB

// NOTE (round-3 lesson): fusing threefry/erfinv/expf into the GEMM epilogue made the
// register allocator spill acc[8][8] to scratch. Sampling stays standalone.
// NOTE (round-4 lesson): k_scatter is write-amplification-bound (101 MB HBM writes
// for a 12.8 MB payload, 8x = 64B-line granularity on random 8B stores) with 0.6%
// VALU. So: (a) cursor atomic removed via rank-from-count, (b) gemm1 co-scheduled
// into the same launch to run on the idle VALU/LDS pipes.

// ---------------- helpers ----------------
__device__ __forceinline__ float2 ld2(const float* p) { return *(const float2*)p; }
__device__ __forceinline__ float2 ld2(const __hip_bfloat16* p) {
    const __hip_bfloat162 h = *(const __hip_bfloat162*)p;
    return make_float2(__bfloat162float(h.x), __bfloat162float(h.y));
}

__device__ __forceinline__ void store8(float* p, const float* v) {
    *(float4*)(p)     = make_float4(v[0], v[1], v[2], v[3]);
    *(float4*)(p + 4) = make_float4(v[4], v[5], v[6], v[7]);
}
__device__ __forceinline__ void store8(__hip_bfloat16* p, const float* v) {
    union { unsigned short us[8]; uint4 q; } u;
#pragma unroll
    for (int i = 0; i < 8; ++i) {
        __hip_bfloat16 b = __float2bfloat16(v[i]);
        unsigned short raw;
        memcpy(&raw, &b, 2);
        u.us[i] = raw;
    }
    *(uint4*)p = u.q;
}

// ---------------- CSR build ----------------
// count + per-edge rank (return value of the atomic): removes the second atomic
// pass — scatter positions become pure loads.
__global__ void k_count_rank(const int* __restrict__ dst, int* __restrict__ counts,
                             int* __restrict__ rank) {
    int e = blockIdx.x * 256 + threadIdx.x;
    if (e < N_EDGES) rank[e] = atomicAdd(&counts[dst[e]], 1);
}

__global__ void k_scan_block(const int* __restrict__ counts, int* __restrict__ partial,
                             int* __restrict__ bsum) {
    __shared__ int s[256];
    int i = blockIdx.x * 256 + threadIdx.x;
    int v = (i < N_NODES) ? counts[i] : 0;
    s[threadIdx.x] = v;
    __syncthreads();
    for (int off = 1; off < 256; off <<= 1) {
        int t = (threadIdx.x >= off) ? s[threadIdx.x - off] : 0;
        __syncthreads();
        s[threadIdx.x] += t;
        __syncthreads();
    }
    if (i < N_NODES) partial[i] = s[threadIdx.x] - v;   // exclusive within block
    if (threadIdx.x == 255) bsum[blockIdx.x] = s[255];
}

__global__ void k_scan_sums(int* __restrict__ bsum, int nb) {
    __shared__ int s[512];
    int v = (threadIdx.x < nb) ? bsum[threadIdx.x] : 0;
    s[threadIdx.x] = v;
    __syncthreads();
    for (int off = 1; off < 512; off <<= 1) {
        int t = (threadIdx.x >= off) ? s[threadIdx.x - off] : 0;
        __syncthreads();
        s[threadIdx.x] += t;
        __syncthreads();
    }
    if (threadIdx.x < nb) bsum[threadIdx.x] = s[threadIdx.x] - v;  // exclusive
}

__global__ void k_finalize(const int* __restrict__ counts, const int* __restrict__ partial,
                           const int* __restrict__ bsum, int* __restrict__ offsets,
                           float* __restrict__ dinv) {
    int i = blockIdx.x * 256 + threadIdx.x;
    if (i < N_NODES) {
        int o = partial[i] + bsum[blockIdx.x];
        offsets[i] = o;
        dinv[i] = rsqrtf((float)(counts[i] + 1));  // deg = in-degree + self loop
    }
    if (i == 0) offsets[N_NODES] = N_EDGES;
}

// ---------------- fat kernel: gemm1 (t1 = x@W1, bf16) || scatter ----------------
// blocks [0, GEMM_GRID_C): proven 128x128 GEMM geometry, no bias (b1 added later).
// blocks [GEMM_GRID_C, +SCAT_GRID_C): edge scatter with deterministic positions.
__global__ __launch_bounds__(256) void k_gemm1_scatter(
    const float* __restrict__ A, const float* __restrict__ W,
    __hip_bfloat16* __restrict__ out,
    const int* __restrict__ src, const int* __restrict__ dst,
    const int* __restrict__ rank, const int* __restrict__ offsets,
    const float* __restrict__ dinv, int2* __restrict__ sorted) {
    __shared__ float Wl[16][128];
    __shared__ float Al[128][16];

    if (blockIdx.x >= GEMM_GRID_C) {
        // ---- scatter path ----
        int e = (blockIdx.x - GEMM_GRID_C) * 256 + threadIdx.x;
        if (e < N_EDGES) {
            int s = src[e], d = dst[e];
            int pos = offsets[d] + rank[e];
            float c = dinv[s] * dinv[d];
            sorted[pos] = make_int2(s, __float_as_int(c));
        }
        return;
    }

    // ---- gemm path ----
    int t = threadIdx.x;
    int R = blockIdx.x * 128;
    int tx = t & 15, ty = t >> 4;
    int c0 = tx * 8;
    int r0 = ty * 8;
    float acc[8][8] = {};

    for (int k0 = 0; k0 < 128; k0 += 16) {
        {
            const float4* Wg = (const float4*)(W + k0 * 128);
            ((float4*)&Wl[0][0])[t] = Wg[t];
            ((float4*)&Wl[0][0])[t + 256] = Wg[t + 256];
        }
        {
#pragma unroll
            for (int ii = 0; ii < 2; ++ii) {
                int id = t + ii * 256;
                int row = id >> 2, c4 = (id & 3) * 4;
                int gr = R + row;
                float4 v = make_float4(0.f, 0.f, 0.f, 0.f);
                if (gr < N_NODES) v = *(const float4*)(A + (size_t)gr * HID + k0 + c4);
                *(float4*)(&Al[row][c4]) = v;
            }
        }
        __syncthreads();

#pragma unroll
        for (int kk4 = 0; kk4 < 4; ++kk4) {
            float4 av4[8];
#pragma unroll
            for (int j = 0; j < 8; ++j) av4[j] = *(const float4*)(&Al[r0 + j][kk4 * 4]);
            const float* av = (const float*)av4;
#pragma unroll
            for (int kk = 0; kk < 4; ++kk) {
                float4 b0 = *(const float4*)(&Wl[kk4 * 4 + kk][c0]);
                float4 b1 = *(const float4*)(&Wl[kk4 * 4 + kk][c0 + 4]);
#pragma unroll
                for (int j = 0; j < 8; ++j) {
                    float a = av[j * 4 + kk];
                    acc[j][0] = fmaf(a, b0.x, acc[j][0]);
                    acc[j][1] = fmaf(a, b0.y, acc[j][1]);
                    acc[j][2] = fmaf(a, b0.z, acc[j][2]);
                    acc[j][3] = fmaf(a, b0.w, acc[j][3]);
                    acc[j][4] = fmaf(a, b1.x, acc[j][4]);
                    acc[j][5] = fmaf(a, b1.y, acc[j][5]);
                    acc[j][6] = fmaf(a, b1.z, acc[j][6]);
                    acc[j][7] = fmaf(a, b1.w, acc[j][7]);
                }
            }
        }
        __syncthreads();
    }

#pragma unroll
    for (int j = 0; j < 8; ++j) {
        int gr = R + r0 + j;
        if (gr >= N_NODES) continue;
        float v[8];
#pragma unroll
        for (int c = 0; c < 8; ++c) v[c] = acc[j][c];
        store8(out + (size_t)gr * HID + c0, v);
    }
}

// ---------------- aggregation: one wave per node, 2 features per lane ----------------
// Exact batches of 16 (16 gathers in flight), single clamped tail batch.
// Both aggregates gather bf16 rows (256 B/row): layer 1 commuted S·(xW) = (S·x)W.

#define AGG_BATCH(U)                                                              \
    {                                                                             \
        int2 sv[U];                                                               \
        float2 xs[U];                                                             \
        _Pragma("unroll") for (int i = 0; i < U; ++i) sv[i] = sorted[e + i];      \
        _Pragma("unroll") for (int i = 0; i < U; ++i)                             \
            xs[i] = ld2(Xf + (size_t)sv[i].x * HID);                              \
        _Pragma("unroll") for (int i = 0; i < U; ++i) {                           \
            float c = __int_as_float(sv[i].y);                                    \
            a0 = fmaf(c, xs[i].x, a0);                                            \
            a1 = fmaf(c, xs[i].y, a1);                                            \
        }                                                                         \
        e += U;                                                                   \
    }

#define AGG_BATCH_CLAMPED(U)                                                      \
    {                                                                             \
        int2 sv[U];                                                               \
        float2 xs[U];                                                             \
        _Pragma("unroll") for (int i = 0; i < U; ++i) {                           \
            int ee = e + i;                                                       \
            sv[i] = sorted[(ee < e1) ? ee : (e1 - 1)];                            \
        }                                                                         \
        _Pragma("unroll") for (int i = 0; i < U; ++i)                             \
            xs[i] = ld2(Xf + (size_t)sv[i].x * HID);                              \
        _Pragma("unroll") for (int i = 0; i < U; ++i) {                           \
            float c = (e + i < e1) ? __int_as_float(sv[i].y) : 0.f;               \
            a0 = fmaf(c, xs[i].x, a0);                                            \
            a1 = fmaf(c, xs[i].y, a1);                                            \
        }                                                                         \
    }

#define AGG_CORE(XTYPE)                                                           \
    int node = (blockIdx.x * 256 + threadIdx.x) >> 6;                             \
    int lane = threadIdx.x & 63;                                                  \
    if (node >= N_NODES) return;                                                  \
    int f = lane * 2;                                                             \
    const XTYPE* __restrict__ Xf = X + f;                                         \
    float di = dinv[node];                                                        \
    float sc = di * di;                                                           \
    float2 xi = ld2(Xf + (size_t)node * HID);                                     \
    float a0 = sc * xi.x, a1 = sc * xi.y;                                         \
    int e = offsets[node], e1 = offsets[node + 1];                                \
    int rem = e1 - e;                                                             \
    while (rem >= 16) {                                                           \
        AGG_BATCH(16);                                                            \
        rem -= 16;                                                                \
    }                                                                             \
    if (rem > 8) {                                                                \
        AGG_BATCH_CLAMPED(16);                                                    \
    } else if (rem > 0) {                                                         \
        AGG_BATCH_CLAMPED(8);                                                     \
    }

// layer-1 aggregate: gathers t1 (bf16), epilogue h = ELU(agg + b1), writes bf16
__global__ __launch_bounds__(256) void k_agg_h(const __hip_bfloat16* __restrict__ X,
                                               const int* __restrict__ offsets,
                                               const int2* __restrict__ sorted,
                                               const float* __restrict__ dinv,
                                               const float* __restrict__ b1,
                                               __hip_bfloat16* __restrict__ out) {
    AGG_CORE(__hip_bfloat16)
    float v0 = a0 + b1[f];
    float v1 = a1 + b1[f + 1];
    v0 = (v0 > 0.f) ? v0 : expm1f(v0);  // ELU(alpha=1)
    v1 = (v1 > 0.f) ? v1 : expm1f(v1);
    __hip_bfloat162 hb;
    hb.x = __float2bfloat16(v0);
    hb.y = __float2bfloat16(v1);
    *(__hip_bfloat162*)(out + (size_t)node * HID + f) = hb;
}

// layer-2 aggregate: gathers h (bf16), writes f32 aggbuf
__global__ __launch_bounds__(256) void k_agg_f32(const __hip_bfloat16* __restrict__ X,
                                                 const int* __restrict__ offsets,
                                                 const int2* __restrict__ sorted,
                                                 const float* __restrict__ dinv,
                                                 float* __restrict__ out) {
    AGG_CORE(__hip_bfloat16)
    *(float2*)(out + (size_t)node * HID + f) = make_float2(a0, a1);
}

// ---------------- GEMM pair: mu and lv in one launch ----------------
// blocks [0, GEMM_GRID_C) -> mu = A@Wmu + bmu; [GEMM_GRID_C, 2*GEMM_GRID_C) -> lv.
// proven geometry: 256 threads, tile 128x128, K chunked by 16, 8x8 per thread.
__global__ __launch_bounds__(256) void k_gemm_pair(const float* __restrict__ A,
                                                   const float* __restrict__ Wmu,
                                                   const float* __restrict__ bmu,
                                                   const float* __restrict__ Wlv,
                                                   const float* __restrict__ blv,
                                                   float* __restrict__ mu,
                                                   float* __restrict__ lv) {
    __shared__ float Wl[16][128];
    __shared__ float Al[128][16];
    int which = (blockIdx.x >= GEMM_GRID_C);
    const float* __restrict__ W = which ? Wlv : Wmu;
    const float* __restrict__ bias = which ? blv : bmu;
    float* __restrict__ out = which ? lv : mu;
    int bx = which ? (blockIdx.x - GEMM_GRID_C) : blockIdx.x;

    int t = threadIdx.x;
    int R = bx * 128;
    int tx = t & 15, ty = t >> 4;
    int c0 = tx * 8;
    int r0 = ty * 8;
    float acc[8][8] = {};

    for (int k0 = 0; k0 < 128; k0 += 16) {
        {
            const float4* Wg = (const float4*)(W + k0 * 128);
            ((float4*)&Wl[0][0])[t] = Wg[t];
            ((float4*)&Wl[0][0])[t + 256] = Wg[t + 256];
        }
        {
#pragma unroll
            for (int ii = 0; ii < 2; ++ii) {
                int id = t + ii * 256;
                int row = id >> 2, c4 = (id & 3) * 4;
                int gr = R + row;
                float4 v = make_float4(0.f, 0.f, 0.f, 0.f);
                if (gr < N_NODES) v = *(const float4*)(A + (size_t)gr * HID + k0 + c4);
                *(float4*)(&Al[row][c4]) = v;
            }
        }
        __syncthreads();

#pragma unroll
        for (int kk4 = 0; kk4 < 4; ++kk4) {
            float4 av4[8];
#pragma unroll
            for (int j = 0; j < 8; ++j) av4[j] = *(const float4*)(&Al[r0 + j][kk4 * 4]);
            const float* av = (const float*)av4;
#pragma unroll
            for (int kk = 0; kk < 4; ++kk) {
                float4 b0 = *(const float4*)(&Wl[kk4 * 4 + kk][c0]);
                float4 b1 = *(const float4*)(&Wl[kk4 * 4 + kk][c0 + 4]);
#pragma unroll
                for (int j = 0; j < 8; ++j) {
                    float a = av[j * 4 + kk];
                    acc[j][0] = fmaf(a, b0.x, acc[j][0]);
                    acc[j][1] = fmaf(a, b0.y, acc[j][1]);
                    acc[j][2] = fmaf(a, b0.z, acc[j][2]);
                    acc[j][3] = fmaf(a, b0.w, acc[j][3]);
                    acc[j][4] = fmaf(a, b1.x, acc[j][4]);
                    acc[j][5] = fmaf(a, b1.y, acc[j][5]);
                    acc[j][6] = fmaf(a, b1.z, acc[j][6]);
                    acc[j][7] = fmaf(a, b1.w, acc[j][7]);
                }
            }
        }
        __syncthreads();
    }

    float bcol[8];
#pragma unroll
    for (int c = 0; c < 8; ++c) bcol[c] = bias[c0 + c];
#pragma unroll
    for (int j = 0; j < 8; ++j) {
        int gr = R + r0 + j;
        if (gr >= N_NODES) continue;
        float v[8];
#pragma unroll
        for (int c = 0; c < 8; ++c) v[c] = acc[j][c] + bcol[c];
        store8(out + (size_t)gr * HID + c0, v);
    }
}

// ---------------- Threefry-2x32 (20 rounds), key = (0, 42) ----------------
__device__ __forceinline__ unsigned rotl32(unsigned x, int r) {
    return (x << r) | (x >> (32 - r));
}

__device__ __forceinline__ void threefry2x32(unsigned x0, unsigned x1, unsigned& o0,
                                             unsigned& o1) {
    const unsigned ks0 = 0u, ks1 = 42u, ks2 = 0x1BD11BDAu ^ 42u;
    x0 += ks0;
    x1 += ks1;
    x0 += x1; x1 = rotl32(x1, 13); x1 ^= x0;
    x0 += x1; x1 = rotl32(x1, 15); x1 ^= x0;
    x0 += x1; x1 = rotl32(x1, 26); x1 ^= x0;
    x0 += x1; x1 = rotl32(x1, 6);  x1 ^= x0;
    x0 += ks1; x1 += ks2 + 1u;
    x0 += x1; x1 = rotl32(x1, 17); x1 ^= x0;
    x0 += x1; x1 = rotl32(x1, 29); x1 ^= x0;
    x0 += x1; x1 = rotl32(x1, 16); x1 ^= x0;
    x0 += x1; x1 = rotl32(x1, 24); x1 ^= x0;
    x0 += ks2; x1 += ks0 + 2u;
    x0 += x1; x1 = rotl32(x1, 13); x1 ^= x0;
    x0 += x1; x1 = rotl32(x1, 15); x1 ^= x0;
    x0 += x1; x1 = rotl32(x1, 26); x1 ^= x0;
    x0 += x1; x1 = rotl32(x1, 6);  x1 ^= x0;
    x0 += ks0; x1 += ks1 + 3u;
    x0 += x1; x1 = rotl32(x1, 17); x1 ^= x0;
    x0 += x1; x1 = rotl32(x1, 29); x1 ^= x0;
    x0 += x1; x1 = rotl32(x1, 16); x1 ^= x0;
    x0 += x1; x1 = rotl32(x1, 24); x1 ^= x0;
    x0 += ks1; x1 += ks2 + 4u;
    x0 += x1; x1 = rotl32(x1, 13); x1 ^= x0;
    x0 += x1; x1 = rotl32(x1, 15); x1 ^= x0;
    x0 += x1; x1 = rotl32(x1, 26); x1 ^= x0;
    x0 += x1; x1 = rotl32(x1, 6);  x1 ^= x0;
    x0 += ks2; x1 += ks0 + 5u;
    o0 = x0;
    o1 = x1;
}

// XLA ErfInv (f32, Giles) — matches CPU XLA expansion used by jax.random.normal.
__device__ __forceinline__ float erfinv_f32(float x) {
    float w = -log1pf(-x * x);
    float p;
    if (w < 5.0f) {
        w -= 2.5f;
        p = 2.81022636e-08f;
        p = fmaf(p, w, 3.43273939e-07f);
        p = fmaf(p, w, -3.5233877e-06f);
        p = fmaf(p, w, -4.39150654e-06f);
        p = fmaf(p, w, 0.00021858087f);
        p = fmaf(p, w, -0.00125372503f);
        p = fmaf(p, w, -0.00417768164f);
        p = fmaf(p, w, 0.246640727f);
        p = fmaf(p, w, 1.50140941f);
    } else {
        w = sqrtf(w) - 3.0f;
        p = -0.000200214257f;
        p = fmaf(p, w, 0.000100950558f);
        p = fmaf(p, w, 0.00134934322f);
        p = fmaf(p, w, -0.00367342844f);
        p = fmaf(p, w, 0.00573950773f);
        p = fmaf(p, w, -0.0076224613f);
        p = fmaf(p, w, 0.00943887047f);
        p = fmaf(p, w, 1.00167406f);
        p = fmaf(p, w, 2.83297682f);
    }
    return p * x;
}

__global__ __launch_bounds__(256) void k_sample(const float* __restrict__ mu,
                                                const float* __restrict__ lv,
                                                float* __restrict__ z) {
    int j = blockIdx.x * 256 + threadIdx.x;
    if (j >= TOT) return;
    unsigned o0, o1;
    threefry2x32(0u, (unsigned)j, o0, o1);
    unsigned bits = o0 ^ o1;
    // uniform in [minval, 1) with minval = nextafter(-1,0); scale rounds to 2.0f
    float f = __uint_as_float((bits >> 9) | 0x3f800000u) - 1.0f;
    float u = f * 2.0f - 0.99999994f;
    u = fmaxf(u, -0.99999994f);
    float eps = 1.41421356f * erfinv_f32(u);
    z[j] = fmaf(eps, expf(0.5f * lv[j]), mu[j]);
}

// ---------------- launch ----------------
extern "C" void kernel_launch(void* const* d_in, const int* in_sizes, int n_in,
                              void* d_out, int out_size, void* d_ws, size_t ws_size,
                              hipStream_t stream) {
    const float* x = (const float*)d_in[0];
    const int* ei = (const int*)d_in[1];
    const float* W1 = (const float*)d_in[2];
    const float* b1 = (const float*)d_in[3];
    const float* Wmu = (const float*)d_in[4];
    const float* bmu = (const float*)d_in[5];
    const float* Wlv = (const float*)d_in[6];
    const float* blv = (const float*)d_in[7];

    float* z = (float*)d_out;
    float* mu = z + (size_t)TOT;
    float* lv = z + 2 * (size_t)TOT;

    char* ws = (char*)d_ws;
    float* aggbuf = (float*)(ws + 0ull);
    __hip_bfloat16* t1buf = (__hip_bfloat16*)(ws + 0ull);  // aliases aggbuf low half
    int* rank = (int*)(ws + 25600000ull);                  // aliases aggbuf high half
    __hip_bfloat16* hbf = (__hip_bfloat16*)(ws + 51200000ull);
    int* counts = (int*)(ws + 76800000ull);
    int* partial = (int*)(ws + 77200000ull);
    int* bsum = (int*)(ws + 77600000ull);
    int* offsets = (int*)(ws + 77602048ull);
    float* dinv = (float*)(ws + 78402176ull);
    int2* sorted = (int2*)(ws + 78802176ull);

    const int* src = ei;
    const int* dst = ei + N_EDGES;

    const int NBLK = (N_NODES + 255) / 256;  // 391
    const int AGG_GRID = (N_NODES * 64 + 255) / 256;

    hipMemsetAsync(counts, 0, N_NODES * sizeof(int), stream);
    k_count_rank<<<SCAT_GRID_C, 256, 0, stream>>>(dst, counts, rank);
    k_scan_block<<<NBLK, 256, 0, stream>>>(counts, partial, bsum);
    k_scan_sums<<<1, 512, 0, stream>>>(bsum, NBLK);
    k_finalize<<<NBLK, 256, 0, stream>>>(counts, partial, bsum, offsets, dinv);

    // fat launch: t1 = x @ W1 (bf16, no bias) co-scheduled with edge scatter
    k_gemm1_scatter<<<GEMM_GRID_C + SCAT_GRID_C, 256, 0, stream>>>(
        x, W1, t1buf, src, dst, rank, offsets, dinv, sorted);

    // layer 1: h = ELU(S·t1 + b1) (bf16)
    k_agg_h<<<AGG_GRID, 256, 0, stream>>>(t1buf, offsets, sorted, dinv, b1, hbf);

    // layer 2: ha = S·h (f32, overwrites t1/rank region); mu and lv in one launch
    k_agg_f32<<<AGG_GRID, 256, 0, stream>>>(hbf, offsets, sorted, dinv, aggbuf);
    k_gemm_pair<<<2 * GEMM_GRID_C, 256, 0, stream>>>(aggbuf, Wmu, bmu, Wlv, blv, mu, lv);

    // z = mu + eps * exp(0.5*lv)   (eps = threefry-normal, key 42); mu/lv L3-hot
    k_sample<<<(TOT + 255) / 256, 256, 0, stream>>>(mu, lv, z);
}

// Round 6
// 585.566 us; speedup vs baseline: 4.9684x; 1.0613x over previous
//
#include <hip/hip_runtime.h>
#include <hip/hip_bf16.h>
#include <cstring>
#include <cstdint>

#define N_NODES 100000
#define N_EDGES 1600000
#define HID 128
#define TOT (N_NODES * HID)   // 12,800,000
#define GEMM_GRID_C 782       // (N_NODES + 127) / 128
#define SCAT_GRID_C 6250      // N_EDGES / 256

// ---------------- workspace layout (bytes) ----------------
// aggbuf region      @ 0           51,200,000
//   ALIASED: t1 bf16[N,128] in [0, 25.6MB) during layer 1 (dead after k_agg_h);
//            ha bf16[N,128] in [0, 25.6MB) during layer 2 (written by k_agg_bf16);
//            rank int[E]    in [25.6MB, 32MB) during CSR build (dead after scatter)
// hbf     bf16[N,128]   @ 51,200,000  25,600,000
// counts  int [N]       @ 76,800,000     400,000
// partial int [N]       @ 77,200,000     400,000
// bsum    int [512]     @ 77,600,000       2,048
// offsets int [N+1]     @ 77,602,048     400,128
// wmu_t   bf16[128][128]@ 78,002,176      32,768   (in old cursor slot)
// wlv_t   bf16[128][128]@ 78,034,944      32,768
// dinv    f32 [N]       @ 78,402,176     400,000
// sorted  int2[E]       @ 78,802,176  12,800,000
// total ~91.6 MB

// NOTE (round-3): fusing threefry/erfinv/expf into a GEMM epilogue spills acc to
// scratch. Sampling stays standalone.
// NOTE (round-4): scatter is 64B-line write-amplification-bound; runs co-scheduled
// with gemm1 in one fat launch; positions are atomic-free (rank from count pass).
// NOTE (round-5): f32 VALU gemm_pair was FMA-issue-bound (VALUBusy 48%, MfmaUtil 0,
// 12.8M LDS bank conflicts, >=42us pure-FMA floor). Replaced with bf16 MFMA
// (16x16x32), B^T-input fragment pattern (m97-style): A-frags and B-frags both
// k-contiguous 16B loads, no LDS. W transposed/cast once by k_prep_w.

// ---------------- helpers ----------------
typedef __bf16 bf16x8 __attribute__((ext_vector_type(8)));
typedef float f32x4 __attribute__((ext_vector_type(4)));

__device__ __forceinline__ float2 ld2(const float* p) { return *(const float2*)p; }
__device__ __forceinline__ float2 ld2(const __hip_bfloat16* p) {
    const __hip_bfloat162 h = *(const __hip_bfloat162*)p;
    return make_float2(__bfloat162float(h.x), __bfloat162float(h.y));
}

__device__ __forceinline__ void store8(float* p, const float* v) {
    *(float4*)(p)     = make_float4(v[0], v[1], v[2], v[3]);
    *(float4*)(p + 4) = make_float4(v[4], v[5], v[6], v[7]);
}
__device__ __forceinline__ void store8(__hip_bfloat16* p, const float* v) {
    union { unsigned short us[8]; uint4 q; } u;
#pragma unroll
    for (int i = 0; i < 8; ++i) {
        __hip_bfloat16 b = __float2bfloat16(v[i]);
        unsigned short raw;
        memcpy(&raw, &b, 2);
        u.us[i] = raw;
    }
    *(uint4*)p = u.q;
}

// ---------------- CSR build ----------------
__global__ void k_count_rank(const int* __restrict__ dst, int* __restrict__ counts,
                             int* __restrict__ rank) {
    int e = blockIdx.x * 256 + threadIdx.x;
    if (e < N_EDGES) rank[e] = atomicAdd(&counts[dst[e]], 1);
}

__global__ void k_scan_block(const int* __restrict__ counts, int* __restrict__ partial,
                             int* __restrict__ bsum) {
    __shared__ int s[256];
    int i = blockIdx.x * 256 + threadIdx.x;
    int v = (i < N_NODES) ? counts[i] : 0;
    s[threadIdx.x] = v;
    __syncthreads();
    for (int off = 1; off < 256; off <<= 1) {
        int t = (threadIdx.x >= off) ? s[threadIdx.x - off] : 0;
        __syncthreads();
        s[threadIdx.x] += t;
        __syncthreads();
    }
    if (i < N_NODES) partial[i] = s[threadIdx.x] - v;   // exclusive within block
    if (threadIdx.x == 255) bsum[blockIdx.x] = s[255];
}

__global__ void k_scan_sums(int* __restrict__ bsum, int nb) {
    __shared__ int s[512];
    int v = (threadIdx.x < nb) ? bsum[threadIdx.x] : 0;
    s[threadIdx.x] = v;
    __syncthreads();
    for (int off = 1; off < 512; off <<= 1) {
        int t = (threadIdx.x >= off) ? s[threadIdx.x - off] : 0;
        __syncthreads();
        s[threadIdx.x] += t;
        __syncthreads();
    }
    if (threadIdx.x < nb) bsum[threadIdx.x] = s[threadIdx.x] - v;  // exclusive
}

__global__ void k_finalize(const int* __restrict__ counts, const int* __restrict__ partial,
                           const int* __restrict__ bsum, int* __restrict__ offsets,
                           float* __restrict__ dinv) {
    int i = blockIdx.x * 256 + threadIdx.x;
    if (i < N_NODES) {
        int o = partial[i] + bsum[blockIdx.x];
        offsets[i] = o;
        dinv[i] = rsqrtf((float)(counts[i] + 1));  // deg = in-degree + self loop
    }
    if (i == 0) offsets[N_NODES] = N_EDGES;
}

// W[128][128] f32 (rows = k) -> Wt[128][128] bf16 (rows = n), for both matrices
__global__ void k_prep_w(const float* __restrict__ Wmu, const float* __restrict__ Wlv,
                         __hip_bfloat16* __restrict__ wmu_t,
                         __hip_bfloat16* __restrict__ wlv_t) {
    int idx = blockIdx.x * 256 + threadIdx.x;
    if (idx < 128 * 128) {
        int k = idx >> 7, n = idx & 127;
        wmu_t[n * 128 + k] = __float2bfloat16(Wmu[idx]);
        wlv_t[n * 128 + k] = __float2bfloat16(Wlv[idx]);
    }
}

// ---------------- fat kernel: gemm1 (t1 = x@W1, bf16) || scatter ----------------
__global__ __launch_bounds__(256) void k_gemm1_scatter(
    const float* __restrict__ A, const float* __restrict__ W,
    __hip_bfloat16* __restrict__ out,
    const int* __restrict__ src, const int* __restrict__ dst,
    const int* __restrict__ rank, const int* __restrict__ offsets,
    const float* __restrict__ dinv, int2* __restrict__ sorted) {
    __shared__ float Wl[16][128];
    __shared__ float Al[128][16];

    if (blockIdx.x >= GEMM_GRID_C) {
        // ---- scatter path ----
        int e = (blockIdx.x - GEMM_GRID_C) * 256 + threadIdx.x;
        if (e < N_EDGES) {
            int s = src[e], d = dst[e];
            int pos = offsets[d] + rank[e];
            float c = dinv[s] * dinv[d];
            sorted[pos] = make_int2(s, __float_as_int(c));
        }
        return;
    }

    // ---- gemm path ----
    int t = threadIdx.x;
    int R = blockIdx.x * 128;
    int tx = t & 15, ty = t >> 4;
    int c0 = tx * 8;
    int r0 = ty * 8;
    float acc[8][8] = {};

    for (int k0 = 0; k0 < 128; k0 += 16) {
        {
            const float4* Wg = (const float4*)(W + k0 * 128);
            ((float4*)&Wl[0][0])[t] = Wg[t];
            ((float4*)&Wl[0][0])[t + 256] = Wg[t + 256];
        }
        {
#pragma unroll
            for (int ii = 0; ii < 2; ++ii) {
                int id = t + ii * 256;
                int row = id >> 2, c4 = (id & 3) * 4;
                int gr = R + row;
                float4 v = make_float4(0.f, 0.f, 0.f, 0.f);
                if (gr < N_NODES) v = *(const float4*)(A + (size_t)gr * HID + k0 + c4);
                *(float4*)(&Al[row][c4]) = v;
            }
        }
        __syncthreads();

#pragma unroll
        for (int kk4 = 0; kk4 < 4; ++kk4) {
            float4 av4[8];
#pragma unroll
            for (int j = 0; j < 8; ++j) av4[j] = *(const float4*)(&Al[r0 + j][kk4 * 4]);
            const float* av = (const float*)av4;
#pragma unroll
            for (int kk = 0; kk < 4; ++kk) {
                float4 b0 = *(const float4*)(&Wl[kk4 * 4 + kk][c0]);
                float4 b1 = *(const float4*)(&Wl[kk4 * 4 + kk][c0 + 4]);
#pragma unroll
                for (int j = 0; j < 8; ++j) {
                    float a = av[j * 4 + kk];
                    acc[j][0] = fmaf(a, b0.x, acc[j][0]);
                    acc[j][1] = fmaf(a, b0.y, acc[j][1]);
                    acc[j][2] = fmaf(a, b0.z, acc[j][2]);
                    acc[j][3] = fmaf(a, b0.w, acc[j][3]);
                    acc[j][4] = fmaf(a, b1.x, acc[j][4]);
                    acc[j][5] = fmaf(a, b1.y, acc[j][5]);
                    acc[j][6] = fmaf(a, b1.z, acc[j][6]);
                    acc[j][7] = fmaf(a, b1.w, acc[j][7]);
                }
            }
        }
        __syncthreads();
    }

#pragma unroll
    for (int j = 0; j < 8; ++j) {
        int gr = R + r0 + j;
        if (gr >= N_NODES) continue;
        float v[8];
#pragma unroll
        for (int c = 0; c < 8; ++c) v[c] = acc[j][c];
        store8(out + (size_t)gr * HID + c0, v);
    }
}

// ---------------- aggregation: one wave per node, 2 features per lane ----------------
#define AGG_BATCH(U)                                                              \
    {                                                                             \
        int2 sv[U];                                                               \
        float2 xs[U];                                                             \
        _Pragma("unroll") for (int i = 0; i < U; ++i) sv[i] = sorted[e + i];      \
        _Pragma("unroll") for (int i = 0; i < U; ++i)                             \
            xs[i] = ld2(Xf + (size_t)sv[i].x * HID);                              \
        _Pragma("unroll") for (int i = 0; i < U; ++i) {                           \
            float c = __int_as_float(sv[i].y);                                    \
            a0 = fmaf(c, xs[i].x, a0);                                            \
            a1 = fmaf(c, xs[i].y, a1);                                            \
        }                                                                         \
        e += U;                                                                   \
    }

#define AGG_BATCH_CLAMPED(U)                                                      \
    {                                                                             \
        int2 sv[U];                                                               \
        float2 xs[U];                                                             \
        _Pragma("unroll") for (int i = 0; i < U; ++i) {                           \
            int ee = e + i;                                                       \
            sv[i] = sorted[(ee < e1) ? ee : (e1 - 1)];                            \
        }                                                                         \
        _Pragma("unroll") for (int i = 0; i < U; ++i)                             \
            xs[i] = ld2(Xf + (size_t)sv[i].x * HID);                              \
        _Pragma("unroll") for (int i = 0; i < U; ++i) {                           \
            float c = (e + i < e1) ? __int_as_float(sv[i].y) : 0.f;               \
            a0 = fmaf(c, xs[i].x, a0);                                            \
            a1 = fmaf(c, xs[i].y, a1);                                            \
        }                                                                         \
    }

#define AGG_CORE(XTYPE)                                                           \
    int node = (blockIdx.x * 256 + threadIdx.x) >> 6;                             \
    int lane = threadIdx.x & 63;                                                  \
    if (node >= N_NODES) return;                                                  \
    int f = lane * 2;                                                             \
    const XTYPE* __restrict__ Xf = X + f;                                         \
    float di = dinv[node];                                                        \
    float sc = di * di;                                                           \
    float2 xi = ld2(Xf + (size_t)node * HID);                                     \
    float a0 = sc * xi.x, a1 = sc * xi.y;                                         \
    int e = offsets[node], e1 = offsets[node + 1];                                \
    int rem = e1 - e;                                                             \
    while (rem >= 16) {                                                           \
        AGG_BATCH(16);                                                            \
        rem -= 16;                                                                \
    }                                                                             \
    if (rem > 8) {                                                                \
        AGG_BATCH_CLAMPED(16);                                                    \
    } else if (rem > 0) {                                                         \
        AGG_BATCH_CLAMPED(8);                                                     \
    }

// layer-1 aggregate: gathers t1 (bf16), epilogue h = ELU(agg + b1), writes bf16
__global__ __launch_bounds__(256) void k_agg_h(const __hip_bfloat16* __restrict__ X,
                                               const int* __restrict__ offsets,
                                               const int2* __restrict__ sorted,
                                               const float* __restrict__ dinv,
                                               const float* __restrict__ b1,
                                               __hip_bfloat16* __restrict__ out) {
    AGG_CORE(__hip_bfloat16)
    float v0 = a0 + b1[f];
    float v1 = a1 + b1[f + 1];
    v0 = (v0 > 0.f) ? v0 : expm1f(v0);  // ELU(alpha=1)
    v1 = (v1 > 0.f) ? v1 : expm1f(v1);
    __hip_bfloat162 hb;
    hb.x = __float2bfloat16(v0);
    hb.y = __float2bfloat16(v1);
    *(__hip_bfloat162*)(out + (size_t)node * HID + f) = hb;
}

// layer-2 aggregate: gathers h (bf16), writes bf16 ha (MFMA A-operand)
__global__ __launch_bounds__(256) void k_agg_bf16(const __hip_bfloat16* __restrict__ X,
                                                  const int* __restrict__ offsets,
                                                  const int2* __restrict__ sorted,
                                                  const float* __restrict__ dinv,
                                                  __hip_bfloat16* __restrict__ out) {
    AGG_CORE(__hip_bfloat16)
    __hip_bfloat162 hb;
    hb.x = __float2bfloat16(a0);
    hb.y = __float2bfloat16(a1);
    *(__hip_bfloat162*)(out + (size_t)node * HID + f) = hb;
}

// ---------------- MFMA GEMM pair: mu and lv in one launch ----------------
// blocks [0, GEMM_GRID_C): mu = ha@Wmu + bmu; [GEMM_GRID_C, 2x): lv.
// Per block: 128 rows x 128 cols, K=128. 4 waves, each 32 rows x 128 cols.
// mfma_f32_16x16x32_bf16; A-frag: A[m=lane&15][k=(lane>>4)*8+j] (k-contiguous 16B);
// B-frag from Wt[n][k]: Wt[n=lane&15][k-contiguous 16B] (m97 B^T pattern);
// C/D: col=lane&15, row=(lane>>4)*4+reg (m89-verified). No LDS.
__global__ __launch_bounds__(256) void k_gemm_pair_mfma(
    const __hip_bfloat16* __restrict__ A,
    const __hip_bfloat16* __restrict__ wmu_t, const float* __restrict__ bmu,
    const __hip_bfloat16* __restrict__ wlv_t, const float* __restrict__ blv,
    float* __restrict__ mu, float* __restrict__ lv) {
    int which = (blockIdx.x >= GEMM_GRID_C);
    const __hip_bfloat16* __restrict__ wt = which ? wlv_t : wmu_t;
    const float* __restrict__ bias = which ? blv : bmu;
    float* __restrict__ out = which ? lv : mu;
    int bx = which ? (blockIdx.x - GEMM_GRID_C) : blockIdx.x;

    int w = threadIdx.x >> 6;        // wave 0..3
    int l = threadIdx.x & 63;
    int l16 = l & 15, lg = l >> 4;   // lane-in-16, group 0..3
    int wrow = bx * 128 + w * 32;    // wave's first output row

    // A fragments: a[mt][ks], mt = 16-row half, ks = K/32 step
    bf16x8 a[2][4];
#pragma unroll
    for (int mt = 0; mt < 2; ++mt) {
#pragma unroll
        for (int ks = 0; ks < 4; ++ks) {
            int row = wrow + mt * 16 + l16;
            int rr = (row < N_NODES) ? row : (N_NODES - 1);  // clamp: pad rows harmless
            a[mt][ks] = *reinterpret_cast<const bf16x8*>(
                A + (size_t)rr * HID + ks * 32 + lg * 8);
        }
    }

    f32x4 acc[2][8];
#pragma unroll
    for (int mt = 0; mt < 2; ++mt)
#pragma unroll
        for (int nt = 0; nt < 8; ++nt) acc[mt][nt] = (f32x4){0.f, 0.f, 0.f, 0.f};

#pragma unroll
    for (int nt = 0; nt < 8; ++nt) {
        bf16x8 b[4];
#pragma unroll
        for (int ks = 0; ks < 4; ++ks)
            b[ks] = *reinterpret_cast<const bf16x8*>(
                wt + (size_t)(nt * 16 + l16) * HID + ks * 32 + lg * 8);
#pragma unroll
        for (int ks = 0; ks < 4; ++ks) {
            acc[0][nt] = __builtin_amdgcn_mfma_f32_16x16x32_bf16(a[0][ks], b[ks],
                                                                acc[0][nt], 0, 0, 0);
            acc[1][nt] = __builtin_amdgcn_mfma_f32_16x16x32_bf16(a[1][ks], b[ks],
                                                                acc[1][nt], 0, 0, 0);
        }
    }

    // epilogue: + bias, store f32. lanes 0-15 cover 16 consecutive cols (64B seg).
#pragma unroll
    for (int nt = 0; nt < 8; ++nt) {
        float bc = bias[nt * 16 + l16];
#pragma unroll
        for (int mt = 0; mt < 2; ++mt) {
#pragma unroll
            for (int r = 0; r < 4; ++r) {
                int gr = wrow + mt * 16 + lg * 4 + r;
                if (gr < N_NODES)
                    out[(size_t)gr * HID + nt * 16 + l16] = acc[mt][nt][r] + bc;
            }
        }
    }
}

// ---------------- Threefry-2x32 (20 rounds), key = (0, 42) ----------------
__device__ __forceinline__ unsigned rotl32(unsigned x, int r) {
    return (x << r) | (x >> (32 - r));
}

__device__ __forceinline__ void threefry2x32(unsigned x0, unsigned x1, unsigned& o0,
                                             unsigned& o1) {
    const unsigned ks0 = 0u, ks1 = 42u, ks2 = 0x1BD11BDAu ^ 42u;
    x0 += ks0;
    x1 += ks1;
    x0 += x1; x1 = rotl32(x1, 13); x1 ^= x0;
    x0 += x1; x1 = rotl32(x1, 15); x1 ^= x0;
    x0 += x1; x1 = rotl32(x1, 26); x1 ^= x0;
    x0 += x1; x1 = rotl32(x1, 6);  x1 ^= x0;
    x0 += ks1; x1 += ks2 + 1u;
    x0 += x1; x1 = rotl32(x1, 17); x1 ^= x0;
    x0 += x1; x1 = rotl32(x1, 29); x1 ^= x0;
    x0 += x1; x1 = rotl32(x1, 16); x1 ^= x0;
    x0 += x1; x1 = rotl32(x1, 24); x1 ^= x0;
    x0 += ks2; x1 += ks0 + 2u;
    x0 += x1; x1 = rotl32(x1, 13); x1 ^= x0;
    x0 += x1; x1 = rotl32(x1, 15); x1 ^= x0;
    x0 += x1; x1 = rotl32(x1, 26); x1 ^= x0;
    x0 += x1; x1 = rotl32(x1, 6);  x1 ^= x0;
    x0 += ks0; x1 += ks1 + 3u;
    x0 += x1; x1 = rotl32(x1, 17); x1 ^= x0;
    x0 += x1; x1 = rotl32(x1, 29); x1 ^= x0;
    x0 += x1; x1 = rotl32(x1, 16); x1 ^= x0;
    x0 += x1; x1 = rotl32(x1, 24); x1 ^= x0;
    x0 += ks1; x1 += ks2 + 4u;
    x0 += x1; x1 = rotl32(x1, 13); x1 ^= x0;
    x0 += x1; x1 = rotl32(x1, 15); x1 ^= x0;
    x0 += x1; x1 = rotl32(x1, 26); x1 ^= x0;
    x0 += x1; x1 = rotl32(x1, 6);  x1 ^= x0;
    x0 += ks2; x1 += ks0 + 5u;
    o0 = x0;
    o1 = x1;
}

// XLA ErfInv (f32, Giles) — matches CPU XLA expansion used by jax.random.normal.
__device__ __forceinline__ float erfinv_f32(float x) {
    float w = -log1pf(-x * x);
    float p;
    if (w < 5.0f) {
        w -= 2.5f;
        p = 2.81022636e-08f;
        p = fmaf(p, w, 3.43273939e-07f);
        p = fmaf(p, w, -3.5233877e-06f);
        p = fmaf(p, w, -4.39150654e-06f);
        p = fmaf(p, w, 0.00021858087f);
        p = fmaf(p, w, -0.00125372503f);
        p = fmaf(p, w, -0.00417768164f);
        p = fmaf(p, w, 0.246640727f);
        p = fmaf(p, w, 1.50140941f);
    } else {
        w = sqrtf(w) - 3.0f;
        p = -0.000200214257f;
        p = fmaf(p, w, 0.000100950558f);
        p = fmaf(p, w, 0.00134934322f);
        p = fmaf(p, w, -0.00367342844f);
        p = fmaf(p, w, 0.00573950773f);
        p = fmaf(p, w, -0.0076224613f);
        p = fmaf(p, w, 0.00943887047f);
        p = fmaf(p, w, 1.00167406f);
        p = fmaf(p, w, 2.83297682f);
    }
    return p * x;
}

__global__ __launch_bounds__(256) void k_sample(const float* __restrict__ mu,
                                                const float* __restrict__ lv,
                                                float* __restrict__ z) {
    int j = blockIdx.x * 256 + threadIdx.x;
    if (j >= TOT) return;
    unsigned o0, o1;
    threefry2x32(0u, (unsigned)j, o0, o1);
    unsigned bits = o0 ^ o1;
    // uniform in [minval, 1) with minval = nextafter(-1,0); scale rounds to 2.0f
    float f = __uint_as_float((bits >> 9) | 0x3f800000u) - 1.0f;
    float u = f * 2.0f - 0.99999994f;
    u = fmaxf(u, -0.99999994f);
    float eps = 1.41421356f * erfinv_f32(u);
    z[j] = fmaf(eps, expf(0.5f * lv[j]), mu[j]);
}

// ---------------- launch ----------------
extern "C" void kernel_launch(void* const* d_in, const int* in_sizes, int n_in,
                              void* d_out, int out_size, void* d_ws, size_t ws_size,
                              hipStream_t stream) {
    const float* x = (const float*)d_in[0];
    const int* ei = (const int*)d_in[1];
    const float* W1 = (const float*)d_in[2];
    const float* b1 = (const float*)d_in[3];
    const float* Wmu = (const float*)d_in[4];
    const float* bmu = (const float*)d_in[5];
    const float* Wlv = (const float*)d_in[6];
    const float* blv = (const float*)d_in[7];

    float* z = (float*)d_out;
    float* mu = z + (size_t)TOT;
    float* lv = z + 2 * (size_t)TOT;

    char* ws = (char*)d_ws;
    __hip_bfloat16* t1buf = (__hip_bfloat16*)(ws + 0ull);   // layer-1 t1
    __hip_bfloat16* habf = (__hip_bfloat16*)(ws + 0ull);    // layer-2 agg (reuses)
    int* rank = (int*)(ws + 25600000ull);                   // dead after scatter
    __hip_bfloat16* hbf = (__hip_bfloat16*)(ws + 51200000ull);
    int* counts = (int*)(ws + 76800000ull);
    int* partial = (int*)(ws + 77200000ull);
    int* bsum = (int*)(ws + 77600000ull);
    int* offsets = (int*)(ws + 77602048ull);
    __hip_bfloat16* wmu_t = (__hip_bfloat16*)(ws + 78002176ull);  // old cursor slot
    __hip_bfloat16* wlv_t = (__hip_bfloat16*)(ws + 78034944ull);
    float* dinv = (float*)(ws + 78402176ull);
    int2* sorted = (int2*)(ws + 78802176ull);

    const int* src = ei;
    const int* dst = ei + N_EDGES;

    const int NBLK = (N_NODES + 255) / 256;  // 391
    const int AGG_GRID = (N_NODES * 64 + 255) / 256;

    hipMemsetAsync(counts, 0, N_NODES * sizeof(int), stream);
    k_prep_w<<<64, 256, 0, stream>>>(Wmu, Wlv, wmu_t, wlv_t);
    k_count_rank<<<SCAT_GRID_C, 256, 0, stream>>>(dst, counts, rank);
    k_scan_block<<<NBLK, 256, 0, stream>>>(counts, partial, bsum);
    k_scan_sums<<<1, 512, 0, stream>>>(bsum, NBLK);
    k_finalize<<<NBLK, 256, 0, stream>>>(counts, partial, bsum, offsets, dinv);

    // fat launch: t1 = x @ W1 (bf16, no bias) co-scheduled with edge scatter
    k_gemm1_scatter<<<GEMM_GRID_C + SCAT_GRID_C, 256, 0, stream>>>(
        x, W1, t1buf, src, dst, rank, offsets, dinv, sorted);

    // layer 1: h = ELU(S·t1 + b1) (bf16)
    k_agg_h<<<AGG_GRID, 256, 0, stream>>>(t1buf, offsets, sorted, dinv, b1, hbf);

    // layer 2: ha = S·h (bf16, overwrites t1/rank region); mu+lv via MFMA
    k_agg_bf16<<<AGG_GRID, 256, 0, stream>>>(hbf, offsets, sorted, dinv, habf);
    k_gemm_pair_mfma<<<2 * GEMM_GRID_C, 256, 0, stream>>>(habf, wmu_t, bmu, wlv_t, blv,
                                                          mu, lv);

    // z = mu + eps * exp(0.5*lv)   (eps = threefry-normal, key 42); mu/lv L3-hot
    k_sample<<<(TOT + 255) / 256, 256, 0, stream>>>(mu, lv, z);
}